// Round 13
// baseline (380.281 us; speedup 1.0000x reference)
//
#include <hip/hip_runtime.h>
#include <hip/hip_bf16.h>
#include <math.h>

// ---------------------------------------------------------------------------
// BNAF flow (DIM=64, HID=32, B=1024).  R13: gemm1 split-K deepened to 4
// (2048 blocks = 8/CU requested; barrier drains overlap across blocks).
// Structure otherwise identical to R12. 14 dispatches.
// ---------------------------------------------------------------------------

#define DIMN 64
#define BATCH 1024
#define HIDF 2048   // DIM*HID
#define SPLITK 4

typedef __attribute__((ext_vector_type(8))) short short8;
typedef __attribute__((ext_vector_type(4))) float floatx4;

__device__ __forceinline__ float softplusf_(float t) {
    return fmaxf(t, 0.f) + log1pf(__expf(-fabsf(t)));
}

__device__ __forceinline__ void gl_lds16(const void* g, void* l) {
    __builtin_amdgcn_global_load_lds(
        (const __attribute__((address_space(1))) unsigned int*)g,
        (__attribute__((address_space(3))) unsigned int*)l, 16, 0, 0);
}

// tanh + sech^2 from ONE exp:  t = e^{-2|p|}; tanh = sign(p)(1-t)/(1+t);
// sech^2 = 4t/(1+t)^2.
__device__ __forceinline__ void tanh_sech2_(float p, float& th, float& s2) {
    float t = __expf(-2.f * fabsf(p));
    float opt = 1.f + t;
    float inv = 1.f / opt;
    th = copysignf((1.f - t) * inv, p);
    s2 = 4.f * t * inv * inv;
}

// ---------------------------------------------------------------------------
// prep row worker: one wave per output row r of W (out_f x INF).
//  wn = exp(dw)*w/sqrt(wsn); eg[r*ib+k] = exp(dw + W[r][c0+k] - 0.5 log wsn)
// ---------------------------------------------------------------------------
template<int INF>
__device__ __forceinline__ void prep_row(
    const float* __restrict__ W, const float* __restrict__ dw,
    void* __restrict__ wn_out, float* __restrict__ eg,
    int r, int lane, int out_f, int ob, int ib, int transpose, int bf16out)
{
    constexpr int NI = INF / 64;
    int d = r / ob;
    int c0 = d * ib;
    int c1 = c0 + ib;
    const float* Wr = W + (size_t)r * INF;

    float vv[NI];
    float ss = 0.f;
#pragma unroll
    for (int i = 0; i < NI; ++i) {
        int c = lane + i * 64;
        float wraw = Wr[c];
        float wv = (c < c0) ? wraw : ((c < c1) ? __expf(wraw) : 0.f);
        vv[i] = wv;
        ss += wv * wv;
    }
    for (int off = 32; off > 0; off >>= 1) ss += __shfl_xor(ss, off, 64);

    float dwr = dw[r];
    float scale = __expf(dwr) / sqrtf(ss);
    float logt = dwr - 0.5f * __logf(ss);

#pragma unroll
    for (int i = 0; i < NI; ++i) {
        int c = lane + i * 64;
        float val = scale * vv[i];
        if (bf16out) {
            ((__hip_bfloat16*)wn_out)[(size_t)r * INF + c] = __float2bfloat16(val);
        } else if (transpose) {
            ((float*)wn_out)[(size_t)c * out_f + r] = val;
        } else {
            ((float*)wn_out)[(size_t)r * INF + c] = val;
        }
    }
    if (lane < ib) eg[(size_t)r * ib + lane] = __expf(logt + Wr[c0 + lane]);
}

struct PrepIn { const float *W0, *dw0, *W1, *dw1, *W2, *dw2; };

// all three flows' preps in ONE launch: grid 3 * (2048+2048+64) = 12480
__global__ __launch_bounds__(64) void prep_mega(
    PrepIn p0, PrepIn p1, PrepIn p2,
    float* __restrict__ wn0T_all, float* __restrict__ eg0_all,
    __hip_bfloat16* __restrict__ wn1_all, float* __restrict__ e1_all,
    __hip_bfloat16* __restrict__ wn2b_all, float* __restrict__ e2_all)
{
    int blk = blockIdx.x;
    int lane = threadIdx.x;
    int f = blk / 4160;
    int rem = blk - f * 4160;
    PrepIn P = (f == 0) ? p0 : ((f == 1) ? p1 : p2);

    float* wn0T = wn0T_all + (size_t)f * DIMN * HIDF;
    float* eg0  = eg0_all  + (size_t)f * HIDF;
    __hip_bfloat16* wn1 = wn1_all + (size_t)f * HIDF * HIDF;
    float* e1   = e1_all   + (size_t)f * HIDF * 32;
    __hip_bfloat16* wn2b = wn2b_all + (size_t)f * DIMN * HIDF;
    float* e2   = e2_all   + (size_t)f * DIMN * 32;

    if (rem < HIDF) {
        prep_row<DIMN>(P.W0, P.dw0, wn0T, eg0, rem, lane, HIDF, 32, 1, 1, 0);
    } else if (rem < 2 * HIDF) {
        prep_row<HIDF>(P.W1, P.dw1, wn1, e1, rem - HIDF, lane, HIDF, 32, 32, 0, 1);
    } else {
        prep_row<HIDF>(P.W2, P.dw2, wn2b, e2, rem - 2 * HIDF, lane, DIMN, 1, 32, 0, 1);
    }
}

// ---------------------------------------------------------------------------
// gemm0 core: pre0 = xs @ wn0T + b0 ; h0 = tanh(pre0) bf16;
// g0e[b,n] = eg0[n] * sech^2(pre0)
// ---------------------------------------------------------------------------
__device__ __forceinline__ void gemm0_core(
    const float xs[16][DIMN], int b0, int n,
    const float* __restrict__ wn0T, const float* __restrict__ bias,
    const float* __restrict__ eg0,
    __hip_bfloat16* __restrict__ h0, float* __restrict__ g0e)
{
    float acc[16];
#pragma unroll
    for (int j = 0; j < 16; ++j) acc[j] = 0.f;

#pragma unroll 4
    for (int c4 = 0; c4 < 16; ++c4) {
        int c = c4 * 4;
        float w0 = wn0T[(size_t)(c + 0) * HIDF + n];
        float w1 = wn0T[(size_t)(c + 1) * HIDF + n];
        float w2 = wn0T[(size_t)(c + 2) * HIDF + n];
        float w3 = wn0T[(size_t)(c + 3) * HIDF + n];
#pragma unroll
        for (int j = 0; j < 16; ++j) {
            float4 x4 = *(const float4*)&xs[j][c];
            acc[j] = fmaf(x4.x, w0, acc[j]);
            acc[j] = fmaf(x4.y, w1, acc[j]);
            acc[j] = fmaf(x4.z, w2, acc[j]);
            acc[j] = fmaf(x4.w, w3, acc[j]);
        }
    }
    float bv = bias[n], egv = eg0[n];
#pragma unroll
    for (int j = 0; j < 16; ++j) {
        float p = acc[j] + bv;
        float th, s2;
        tanh_sech2_(p, th, s2);
        size_t idx = (size_t)(b0 + j) * HIDF + n;
        h0[idx] = __float2bfloat16(th);
        g0e[idx] = egv * s2;
    }
}

// flow-0 gemm0: reads x directly. grid (8, 64), 256 threads.
__global__ __launch_bounds__(256) void gemm0_act(
    const float* __restrict__ xin, const float* __restrict__ wn0T,
    const float* __restrict__ bias, const float* __restrict__ eg0,
    __hip_bfloat16* __restrict__ h0, float* __restrict__ g0e)
{
    __shared__ float xs[16][DIMN];
    int b0 = blockIdx.y * 16;
    {
        const float4* src = (const float4*)(xin + (size_t)b0 * DIMN);
        ((float4*)xs)[threadIdx.x] = src[threadIdx.x];
    }
    __syncthreads();
    int n = blockIdx.x * 256 + threadIdx.x;
    gemm0_core(xs, b0, n, wn0T, bias, eg0, h0, g0e);
}

// ---------------------------------------------------------------------------
// gemm1_part: partial[kc][m][n] = sum_{k in chunk kc} h0[m,k]*wn1[n,k] (bf16)
// 64x64 tile, BK=64, XOR chunk swizzle kc^(row&7) (0 conflicts - R10),
// flat scalar staging pointers (VGPR-lean), trivial epilogue.
// grid (32, 16, SPLITK=4) = 2048 blocks = 8 blocks/CU requested.
// ---------------------------------------------------------------------------
#define G1BK 64
__global__ __launch_bounds__(256) void gemm1_part(
    const __hip_bfloat16* __restrict__ A, const __hip_bfloat16* __restrict__ B,
    __hip_bfloat16* __restrict__ part)
{
    __shared__ short As[64 * 64];   // 8 KB [64 m][64 k] swizzled
    __shared__ short Bs[64 * 64];   // 8 KB [64 n][64 k] swizzled
    const int K = HIDF, N = HIDF;
    int tid = threadIdx.x;
    int lane = tid & 63;
    int wave = tid >> 6;
    int m0 = blockIdx.y * 64;
    int n0 = blockIdx.x * 64;
    int kbase = blockIdx.z * (K / SPLITK);
    int wr = wave & 1;    // m half (32 rows)
    int wc = wave >> 1;   // n half (32 cols)

    int rf = lane & 15;
    int q = lane >> 4;    // 0..3

    // staging: 512 chunks/matrix; thread handles chunks tid and tid+256.
    // chunk c: row = c>>3, slot kc = c&7; fetch global chunk kc^(row&7).
    int r0c = tid >> 3,          k0c = (tid & 7) ^ (r0c & 7);
    int r1c = (tid + 256) >> 3,  k1c = (tid & 7) ^ (r1c & 7);
    const char* agp0 = (const char*)A + ((size_t)(m0 + r0c) * K + kbase) * 2 + k0c * 16;
    const char* agp1 = (const char*)A + ((size_t)(m0 + r1c) * K + kbase) * 2 + k1c * 16;
    const char* bgp0 = (const char*)B + ((size_t)(n0 + r0c) * K + kbase) * 2 + k0c * 16;
    const char* bgp1 = (const char*)B + ((size_t)(n0 + r1c) * K + kbase) * 2 + k1c * 16;
    char* alds0 = (char*)As + tid * 16;
    char* alds1 = (char*)As + 4096 + tid * 16;
    char* blds0 = (char*)Bs + tid * 16;
    char* blds1 = (char*)Bs + 4096 + tid * 16;

    floatx4 acc[2][2];
#pragma unroll
    for (int i = 0; i < 2; ++i)
#pragma unroll
        for (int j = 0; j < 2; ++j) acc[i][j] = (floatx4){0.f, 0.f, 0.f, 0.f};

    int rowA0 = wr * 32 + rf;
    int rowB0 = wc * 32 + rf;

    for (int k0 = 0; k0 < K / SPLITK; k0 += G1BK) {
        size_t kb = (size_t)k0 * 2;
        __syncthreads();
        gl_lds16(agp0 + kb, alds0);
        gl_lds16(agp1 + kb, alds1);
        gl_lds16(bgp0 + kb, blds0);
        gl_lds16(bgp1 + kb, blds1);
        __syncthreads();

#pragma unroll
        for (int s = 0; s < 2; ++s) {
            short8 af0, af1, bf0, bf1;
            {
                int row = rowA0;
                af0 = *(const short8*)&As[row * 64 + (((s * 4 + q) ^ (row & 7)) * 8)];
                row = rowA0 + 16;
                af1 = *(const short8*)&As[row * 64 + (((s * 4 + q) ^ (row & 7)) * 8)];
                row = rowB0;
                bf0 = *(const short8*)&Bs[row * 64 + (((s * 4 + q) ^ (row & 7)) * 8)];
                row = rowB0 + 16;
                bf1 = *(const short8*)&Bs[row * 64 + (((s * 4 + q) ^ (row & 7)) * 8)];
            }
            acc[0][0] = __builtin_amdgcn_mfma_f32_16x16x32_bf16(af0, bf0, acc[0][0], 0, 0, 0);
            acc[0][1] = __builtin_amdgcn_mfma_f32_16x16x32_bf16(af0, bf1, acc[0][1], 0, 0, 0);
            acc[1][0] = __builtin_amdgcn_mfma_f32_16x16x32_bf16(af1, bf0, acc[1][0], 0, 0, 0);
            acc[1][1] = __builtin_amdgcn_mfma_f32_16x16x32_bf16(af1, bf1, acc[1][1], 0, 0, 0);
        }
    }

    // trivial epilogue: store partials as bf16
    __hip_bfloat16* pk = part + (size_t)blockIdx.z * BATCH * HIDF;
    int col = lane & 15;
    int rq = (lane >> 4) * 4;
#pragma unroll
    for (int i = 0; i < 2; ++i) {
#pragma unroll
        for (int j = 0; j < 2; ++j) {
            int n = n0 + wc * 32 + j * 16 + col;
#pragma unroll
            for (int r = 0; r < 4; ++r) {
                int m = m0 + wr * 32 + i * 16 + rq + r;
                pk[(size_t)m * N + n] = __float2bfloat16(acc[i][j][r]);
            }
        }
    }
}

// ---------------------------------------------------------------------------
// act_grad: pre1 = sum_kc part[kc] + bias;
//   h1b = bf16(tanh(pre1));
//   grad1e = sech^2(pre1) * sum_k E1[n,k]*g0e[b,(n&~31)+k]
// Tile 64 b x 64 n. E1 row per-thread in registers; g0e tile in LDS.
// grid (32, 16), 256 threads (4 b-groups x 64 n).
// ---------------------------------------------------------------------------
__global__ __launch_bounds__(256) void act_grad(
    const __hip_bfloat16* __restrict__ part, const float* __restrict__ bias,
    const float* __restrict__ e1, const float* __restrict__ g0e,
    __hip_bfloat16* __restrict__ h1b, float* __restrict__ grad1e)
{
    __shared__ float g0s[64 * 68];   // 17408 B
    int tid = threadIdx.x;
    int n0 = blockIdx.x * 64;
    int b0 = blockIdx.y * 64;

    // stage g0e tile [64 b][64 c] (pad 68)
#pragma unroll
    for (int s = tid; s < 1024; s += 256) {
        int row = s >> 4, c4 = s & 15;
        *(float4*)&g0s[row * 68 + c4 * 4] =
            *(const float4*)&g0e[(size_t)(b0 + row) * HIDF + n0 + c4 * 4];
    }

    int g = tid >> 6;        // b-group 0..3
    int nl = tid & 63;       // local n
    int n = n0 + nl;

    // E1 row for this n into registers (32 floats)
    float4 er[8];
    const float4* e1r = (const float4*)(e1 + (size_t)n * 32);
#pragma unroll
    for (int qq = 0; qq < 8; ++qq) er[qq] = e1r[qq];

    float bv = bias[n];
    int kb2 = nl & 32;
    const __hip_bfloat16* p0 = part;
    const __hip_bfloat16* p1 = part + (size_t)BATCH * HIDF;
    const __hip_bfloat16* p2 = part + (size_t)2 * BATCH * HIDF;
    const __hip_bfloat16* p3 = part + (size_t)3 * BATCH * HIDF;

    __syncthreads();

#pragma unroll
    for (int t = 0; t < 16; ++t) {
        int bl = g * 16 + t;
        int b = b0 + bl;
        size_t idx = (size_t)b * HIDF + n;
        float pre = __bfloat162float(p0[idx]) + __bfloat162float(p1[idx])
                  + __bfloat162float(p2[idx]) + __bfloat162float(p3[idx]) + bv;
        float th, s2;
        tanh_sech2_(pre, th, s2);
        const float* g0row = &g0s[bl * 68 + kb2];
        float dot = 0.f;
#pragma unroll
        for (int qq = 0; qq < 8; ++qq) {
            float4 gv = *(const float4*)&g0row[qq * 4];
            dot = fmaf(gv.x, er[qq].x, dot);
            dot = fmaf(gv.y, er[qq].y, dot);
            dot = fmaf(gv.z, er[qq].z, dot);
            dot = fmaf(gv.w, er[qq].w, dot);
        }
        h1b[idx] = __float2bfloat16(th);
        grad1e[idx] = dot * s2;
    }
}

// ---------------------------------------------------------------------------
// gemm2_splitk: out2p[kc][m][n] = sum_{k in chunk kc} h1b[m,k]*wn2b[n,k]
// grid (16 kchunks, 16 mtiles), 256 threads. XOR-swizzled LDS staging.
// ---------------------------------------------------------------------------
__global__ __launch_bounds__(256) void gemm2_splitk(
    const __hip_bfloat16* __restrict__ A, const __hip_bfloat16* __restrict__ B,
    float* __restrict__ out2p)
{
    __shared__ short As2[64 * 128];   // 16 KB [m][k]
    __shared__ short Bs2[64 * 128];   // 16 KB [n][k]
    int tid = threadIdx.x;
    int lane = tid & 63;
    int wave = tid >> 6;
    int k0 = blockIdx.x * 128;
    int m0 = blockIdx.y * 64;

    const char* Ab = (const char*)A;
    const char* Bb = (const char*)B;
#pragma unroll
    for (int is = 0; is < 4; ++is) {
        int ci = is * 256 + tid;          // row = ci>>4, slot kc = ci&15
        int row = ci >> 4, kc = ci & 15;
        int gkc = kc ^ (row & 15);        // XOR swizzle (matches read side)
        char* ldsbase_a = (char*)As2 + (is * 256 + wave * 64) * 16;
        char* ldsbase_b = (char*)Bs2 + (is * 256 + wave * 64) * 16;
        gl_lds16(Ab + ((size_t)(m0 + row) * HIDF + k0) * 2 + gkc * 16, ldsbase_a);
        gl_lds16(Bb + ((size_t)row * HIDF + k0) * 2 + gkc * 16, ldsbase_b);
    }
    __syncthreads();

    int rf = lane & 15;
    int q = lane >> 4;

    floatx4 acc[4];
#pragma unroll
    for (int j = 0; j < 4; ++j) acc[j] = (floatx4){0.f, 0.f, 0.f, 0.f};

#pragma unroll
    for (int s = 0; s < 4; ++s) {
        int rowa = wave * 16 + rf;
        int cpa = (s * 4 + q) ^ rf;
        short8 af = *(const short8*)&As2[rowa * 128 + cpa * 8];
#pragma unroll
        for (int j = 0; j < 4; ++j) {
            int rowb = j * 16 + rf;
            int cpb = (s * 4 + q) ^ rf;
            short8 bfv = *(const short8*)&Bs2[rowb * 128 + cpb * 8];
            acc[j] = __builtin_amdgcn_mfma_f32_16x16x32_bf16(af, bfv, acc[j], 0, 0, 0);
        }
    }

    float* outk = out2p + (size_t)blockIdx.x * BATCH * DIMN;
    int col = lane & 15;
    int rq = (lane >> 4) * 4;
#pragma unroll
    for (int j = 0; j < 4; ++j) {
#pragma unroll
        for (int r = 0; r < 4; ++r) {
            int m = m0 + wave * 16 + rq + r;
            outk[(size_t)m * DIMN + j * 16 + col] = acc[j][r];
        }
    }
}

// ---------------------------------------------------------------------------
// tail_gemm0: flows f -> f+1 transition fused with next flow's gemm0.
// gF[b,n] = log( sum_k E2[n,k] * grad1e[b, n*32+k] )   (exp-domain dot)
// ---------------------------------------------------------------------------
__global__ __launch_bounds__(256) void tail_gemm0(
    const float* __restrict__ out2p, const float* __restrict__ b2prev,
    const float* __restrict__ e2prev, const float* __restrict__ grad1e,
    const float* __restrict__ x_cur, const float* __restrict__ gate,
    float* __restrict__ x_next, float* __restrict__ ldj, int accum_ldj,
    const float* __restrict__ wn0T, const float* __restrict__ bias0,
    const float* __restrict__ eg0n, __hip_bfloat16* __restrict__ h0,
    float* __restrict__ g0e)
{
    __shared__ float xs[16][DIMN];
    int tid = threadIdx.x;
    int b0 = blockIdx.y * 16;

    {
        int bl = tid >> 4;            // local batch 0..15
        int n4 = (tid & 15) * 4;
        int b = b0 + bl;
        float4 o4 = *(const float4*)&b2prev[n4];
#pragma unroll
        for (int p = 0; p < 16; ++p) {
            float4 t = *(const float4*)&out2p[(size_t)p * BATCH * DIMN + (size_t)b * DIMN + n4];
            o4.x += t.x; o4.y += t.y; o4.z += t.z; o4.w += t.w;
        }
        float gt = gate[0];
        float sg = 1.f / (1.f + __expf(-gt));
        float4 xc = *(const float4*)&x_cur[(size_t)b * DIMN + n4];
        float4 xo;
        xo.x = sg * o4.x + (1.f - sg) * xc.x;
        xo.y = sg * o4.y + (1.f - sg) * xc.y;
        xo.z = sg * o4.z + (1.f - sg) * xc.z;
        xo.w = sg * o4.w + (1.f - sg) * xc.w;
        xs[bl][63 - n4] = xo.x;
        xs[bl][62 - n4] = xo.y;
        xs[bl][61 - n4] = xo.z;
        xs[bl][60 - n4] = xo.w;

        if (blockIdx.x == 0) {
            float4 rv; rv.x = xo.w; rv.y = xo.z; rv.z = xo.y; rv.w = xo.x;
            *(float4*)&x_next[(size_t)b * DIMN + (60 - n4)] = rv;

            float spgt = softplusf_(gt);
            float cl = 0.f;
#pragma unroll
            for (int q = 0; q < 4; ++q) {
                int n = n4 + q;
                const float4* gr = (const float4*)&grad1e[(size_t)b * HIDF + n * 32];
                const float4* gc = (const float4*)&e2prev[n * 32];
                float s = 0.f;
#pragma unroll
                for (int u = 0; u < 8; ++u) {
                    float4 a = gr[u], c = gc[u];
                    s = fmaf(a.x, c.x, s);
                    s = fmaf(a.y, c.y, s);
                    s = fmaf(a.z, c.z, s);
                    s = fmaf(a.w, c.w, s);
                }
                float gF = __logf(s);
                cl += softplusf_(gF + gt) - spgt;
            }
            cl += __shfl_xor(cl, 1, 64);
            cl += __shfl_xor(cl, 2, 64);
            cl += __shfl_xor(cl, 4, 64);
            cl += __shfl_xor(cl, 8, 64);
            if ((tid & 15) == 0) ldj[b] = accum_ldj ? (ldj[b] + cl) : cl;
        }
    }
    __syncthreads();

    int n = blockIdx.x * 256 + tid;
    gemm0_core(xs, b0, n, wn0T, bias0, eg0n, h0, g0e);
}

// ---------------------------------------------------------------------------
// tail_final (flow 2): out[b] = ldj[b] + sum_n(gF - 0.5*o^2 - 0.5*log(2pi))
// ---------------------------------------------------------------------------
__global__ __launch_bounds__(256) void tail_final(
    const float* __restrict__ out2p, const float* __restrict__ b2,
    const float* __restrict__ e2, const float* __restrict__ grad1e,
    const float* __restrict__ ldj, float* __restrict__ out)
{
    int tid = threadIdx.x;
    int b = blockIdx.x * 4 + (tid >> 6);
    int n = tid & 63;

    float o = b2[n];
#pragma unroll
    for (int p = 0; p < 16; ++p)
        o += out2p[(size_t)p * BATCH * DIMN + (size_t)b * DIMN + n];

    const float4* gr = (const float4*)(grad1e + (size_t)b * HIDF + n * 32);
    const float4* gc = (const float4*)(e2 + n * 32);
    float s = 0.f;
#pragma unroll
    for (int q = 0; q < 8; ++q) {
        float4 a = gr[q], c = gc[q];
        s = fmaf(a.x, c.x, s);
        s = fmaf(a.y, c.y, s);
        s = fmaf(a.z, c.z, s);
        s = fmaf(a.w, c.w, s);
    }
    float gF = __logf(fmaxf(s, 1e-45f));

    float contrib = gF - 0.5f * o * o - 0.91893853320467274f; // -0.5*log(2pi)
    for (int off = 32; off > 0; off >>= 1) contrib += __shfl_xor(contrib, off, 64);
    if (n == 0) out[b] = ldj[b] + contrib;
}

// ---------------------------------------------------------------------------
extern "C" void kernel_launch(void* const* d_in, const int* in_sizes, int n_in,
                              void* d_out, int out_size, void* d_ws, size_t ws_size,
                              hipStream_t stream)
{
    (void)in_sizes; (void)n_in; (void)out_size; (void)ws_size;

    const float* x = (const float*)d_in[0];
    const float* gates[2] = { (const float*)d_in[28], (const float*)d_in[29] };

    char* ws = (char*)d_ws;
    size_t ofs = 0;
    auto alloc = [&](size_t bytes) { char* p = ws + ofs; ofs += (bytes + 255) & ~(size_t)255; return p; };

    __hip_bfloat16* wn1_all  = (__hip_bfloat16*)alloc((size_t)3 * HIDF * HIDF * 2);  // 24 MB
    __hip_bfloat16* wn2b_all = (__hip_bfloat16*)alloc((size_t)3 * DIMN * HIDF * 2);
    float* wn0T_all = (float*)alloc((size_t)3 * DIMN * HIDF * 4);
    float* eg0_all  = (float*)alloc((size_t)3 * HIDF * 4);
    float* e1_all   = (float*)alloc((size_t)3 * HIDF * 32 * 4);
    float* e2_all   = (float*)alloc((size_t)3 * DIMN * 32 * 4);
    __hip_bfloat16* h0   = (__hip_bfloat16*)alloc((size_t)BATCH * HIDF * 2);
    __hip_bfloat16* h1b  = (__hip_bfloat16*)alloc((size_t)BATCH * HIDF * 2);
    __hip_bfloat16* part = (__hip_bfloat16*)alloc((size_t)SPLITK * BATCH * HIDF * 2);  // 16 MB
    float* g0e    = (float*)alloc((size_t)BATCH * HIDF * 4);
    float* grad1e = (float*)alloc((size_t)BATCH * HIDF * 4);
    float* out2p  = (float*)alloc((size_t)16 * BATCH * DIMN * 4);
    float* x1     = (float*)alloc((size_t)BATCH * DIMN * 4);
    float* x2     = (float*)alloc((size_t)BATCH * DIMN * 4);
    float* ldj    = (float*)alloc(BATCH * 4);
    float* outp   = (float*)d_out;

    auto W = [&](int f, int i) { return (const float*)d_in[1 + f * 9 + i]; };

    PrepIn p0 = { W(0,0), W(0,1), W(0,3), W(0,4), W(0,6), W(0,7) };
    PrepIn p1 = { W(1,0), W(1,1), W(1,3), W(1,4), W(1,6), W(1,7) };
    PrepIn p2 = { W(2,0), W(2,1), W(2,3), W(2,4), W(2,6), W(2,7) };

    prep_mega<<<dim3(3 * 4160), dim3(64), 0, stream>>>(
        p0, p1, p2, wn0T_all, eg0_all, wn1_all, e1_all, wn2b_all, e2_all);

    gemm0_act<<<dim3(8, BATCH / 16), dim3(256), 0, stream>>>(
        x, wn0T_all, W(0,2), eg0_all, h0, g0e);

    const float* xcur = x;
    float* xnexts[2] = { x1, x2 };

    for (int f = 0; f < 3; ++f) {
        size_t fo1 = (size_t)f * HIDF * HIDF;
        size_t fo2 = (size_t)f * DIMN * HIDF;

        gemm1_part<<<dim3(HIDF / 64, BATCH / 64, SPLITK), dim3(256), 0, stream>>>(
            h0, wn1_all + fo1, part);

        act_grad<<<dim3(HIDF / 64, BATCH / 64), dim3(256), 0, stream>>>(
            part, W(f,5), e1_all + (size_t)f * HIDF * 32, g0e, h1b, grad1e);

        gemm2_splitk<<<dim3(HIDF / 128, BATCH / 64), dim3(256), 0, stream>>>(
            h1b, wn2b_all + fo2, out2p);

        if (f < 2) {
            tail_gemm0<<<dim3(8, BATCH / 16), dim3(256), 0, stream>>>(
                out2p, W(f,8), e2_all + (size_t)f * DIMN * 32, grad1e,
                xcur, gates[f], xnexts[f], ldj, f,
                wn0T_all + (size_t)(f + 1) * DIMN * HIDF, W(f + 1, 2),
                eg0_all + (size_t)(f + 1) * HIDF, h0, g0e);
            xcur = xnexts[f];
        } else {
            tail_final<<<dim3(BATCH / 4), dim3(256), 0, stream>>>(
                out2p, W(2,8), e2_all + (size_t)2 * DIMN * 32, grad1e, ldj, outp);
        }
    }
}

// Round 14
// 323.932 us; speedup vs baseline: 1.1740x; 1.1740x over previous
//
#include <hip/hip_runtime.h>
#include <hip/hip_bf16.h>
#include <math.h>

// ---------------------------------------------------------------------------
// BNAF flow (DIM=64, HID=32, B=1024).  R14: R12 config (gemm1 split-K=2)
// + gemm2 fused into act_grad (h1 tile stays in LDS; 32-way out2 partials).
// 11 dispatches.
// ---------------------------------------------------------------------------

#define DIMN 64
#define BATCH 1024
#define HIDF 2048   // DIM*HID
#define SPLITK 2
#define NT2 32      // out2 partial count (= HIDF/64 n-tiles)

typedef __attribute__((ext_vector_type(8))) short short8;
typedef __attribute__((ext_vector_type(4))) float floatx4;

__device__ __forceinline__ float softplusf_(float t) {
    return fmaxf(t, 0.f) + log1pf(__expf(-fabsf(t)));
}

__device__ __forceinline__ void gl_lds16(const void* g, void* l) {
    __builtin_amdgcn_global_load_lds(
        (const __attribute__((address_space(1))) unsigned int*)g,
        (__attribute__((address_space(3))) unsigned int*)l, 16, 0, 0);
}

// tanh + sech^2 from ONE exp:  t = e^{-2|p|}; tanh = sign(p)(1-t)/(1+t);
// sech^2 = 4t/(1+t)^2.
__device__ __forceinline__ void tanh_sech2_(float p, float& th, float& s2) {
    float t = __expf(-2.f * fabsf(p));
    float opt = 1.f + t;
    float inv = 1.f / opt;
    th = copysignf((1.f - t) * inv, p);
    s2 = 4.f * t * inv * inv;
}

// ---------------------------------------------------------------------------
// prep row worker: one wave per output row r of W (out_f x INF).
//  wn = exp(dw)*w/sqrt(wsn); eg[r*ib+k] = exp(dw + W[r][c0+k] - 0.5 log wsn)
// ---------------------------------------------------------------------------
template<int INF>
__device__ __forceinline__ void prep_row(
    const float* __restrict__ W, const float* __restrict__ dw,
    void* __restrict__ wn_out, float* __restrict__ eg,
    int r, int lane, int out_f, int ob, int ib, int transpose, int bf16out)
{
    constexpr int NI = INF / 64;
    int d = r / ob;
    int c0 = d * ib;
    int c1 = c0 + ib;
    const float* Wr = W + (size_t)r * INF;

    float vv[NI];
    float ss = 0.f;
#pragma unroll
    for (int i = 0; i < NI; ++i) {
        int c = lane + i * 64;
        float wraw = Wr[c];
        float wv = (c < c0) ? wraw : ((c < c1) ? __expf(wraw) : 0.f);
        vv[i] = wv;
        ss += wv * wv;
    }
    for (int off = 32; off > 0; off >>= 1) ss += __shfl_xor(ss, off, 64);

    float dwr = dw[r];
    float scale = __expf(dwr) / sqrtf(ss);
    float logt = dwr - 0.5f * __logf(ss);

#pragma unroll
    for (int i = 0; i < NI; ++i) {
        int c = lane + i * 64;
        float val = scale * vv[i];
        if (bf16out) {
            ((__hip_bfloat16*)wn_out)[(size_t)r * INF + c] = __float2bfloat16(val);
        } else if (transpose) {
            ((float*)wn_out)[(size_t)c * out_f + r] = val;
        } else {
            ((float*)wn_out)[(size_t)r * INF + c] = val;
        }
    }
    if (lane < ib) eg[(size_t)r * ib + lane] = __expf(logt + Wr[c0 + lane]);
}

struct PrepIn { const float *W0, *dw0, *W1, *dw1, *W2, *dw2; };

// all three flows' preps in ONE launch: grid 3 * (2048+2048+64) = 12480
__global__ __launch_bounds__(64) void prep_mega(
    PrepIn p0, PrepIn p1, PrepIn p2,
    float* __restrict__ wn0T_all, float* __restrict__ eg0_all,
    __hip_bfloat16* __restrict__ wn1_all, float* __restrict__ e1_all,
    __hip_bfloat16* __restrict__ wn2b_all, float* __restrict__ e2_all)
{
    int blk = blockIdx.x;
    int lane = threadIdx.x;
    int f = blk / 4160;
    int rem = blk - f * 4160;
    PrepIn P = (f == 0) ? p0 : ((f == 1) ? p1 : p2);

    float* wn0T = wn0T_all + (size_t)f * DIMN * HIDF;
    float* eg0  = eg0_all  + (size_t)f * HIDF;
    __hip_bfloat16* wn1 = wn1_all + (size_t)f * HIDF * HIDF;
    float* e1   = e1_all   + (size_t)f * HIDF * 32;
    __hip_bfloat16* wn2b = wn2b_all + (size_t)f * DIMN * HIDF;
    float* e2   = e2_all   + (size_t)f * DIMN * 32;

    if (rem < HIDF) {
        prep_row<DIMN>(P.W0, P.dw0, wn0T, eg0, rem, lane, HIDF, 32, 1, 1, 0);
    } else if (rem < 2 * HIDF) {
        prep_row<HIDF>(P.W1, P.dw1, wn1, e1, rem - HIDF, lane, HIDF, 32, 32, 0, 1);
    } else {
        prep_row<HIDF>(P.W2, P.dw2, wn2b, e2, rem - 2 * HIDF, lane, DIMN, 1, 32, 0, 1);
    }
}

// ---------------------------------------------------------------------------
// gemm0 core: pre0 = xs @ wn0T + b0 ; h0 = tanh(pre0) bf16;
// g0e[b,n] = eg0[n] * sech^2(pre0)
// ---------------------------------------------------------------------------
__device__ __forceinline__ void gemm0_core(
    const float xs[16][DIMN], int b0, int n,
    const float* __restrict__ wn0T, const float* __restrict__ bias,
    const float* __restrict__ eg0,
    __hip_bfloat16* __restrict__ h0, float* __restrict__ g0e)
{
    float acc[16];
#pragma unroll
    for (int j = 0; j < 16; ++j) acc[j] = 0.f;

#pragma unroll 4
    for (int c4 = 0; c4 < 16; ++c4) {
        int c = c4 * 4;
        float w0 = wn0T[(size_t)(c + 0) * HIDF + n];
        float w1 = wn0T[(size_t)(c + 1) * HIDF + n];
        float w2 = wn0T[(size_t)(c + 2) * HIDF + n];
        float w3 = wn0T[(size_t)(c + 3) * HIDF + n];
#pragma unroll
        for (int j = 0; j < 16; ++j) {
            float4 x4 = *(const float4*)&xs[j][c];
            acc[j] = fmaf(x4.x, w0, acc[j]);
            acc[j] = fmaf(x4.y, w1, acc[j]);
            acc[j] = fmaf(x4.z, w2, acc[j]);
            acc[j] = fmaf(x4.w, w3, acc[j]);
        }
    }
    float bv = bias[n], egv = eg0[n];
#pragma unroll
    for (int j = 0; j < 16; ++j) {
        float p = acc[j] + bv;
        float th, s2;
        tanh_sech2_(p, th, s2);
        size_t idx = (size_t)(b0 + j) * HIDF + n;
        h0[idx] = __float2bfloat16(th);
        g0e[idx] = egv * s2;
    }
}

// flow-0 gemm0: reads x directly. grid (8, 64), 256 threads.
__global__ __launch_bounds__(256) void gemm0_act(
    const float* __restrict__ xin, const float* __restrict__ wn0T,
    const float* __restrict__ bias, const float* __restrict__ eg0,
    __hip_bfloat16* __restrict__ h0, float* __restrict__ g0e)
{
    __shared__ float xs[16][DIMN];
    int b0 = blockIdx.y * 16;
    {
        const float4* src = (const float4*)(xin + (size_t)b0 * DIMN);
        ((float4*)xs)[threadIdx.x] = src[threadIdx.x];
    }
    __syncthreads();
    int n = blockIdx.x * 256 + threadIdx.x;
    gemm0_core(xs, b0, n, wn0T, bias, eg0, h0, g0e);
}

// ---------------------------------------------------------------------------
// gemm1_part: partial[kc][m][n] = sum_{k in chunk kc} h0[m,k]*wn1[n,k] (bf16)
// 64x64 tile, BK=64, XOR chunk swizzle kc^(row&7), flat scalar staging
// pointers (VGPR-lean), trivial epilogue. grid (32, 16, 2) = 1024 blocks.
// ---------------------------------------------------------------------------
#define G1BK 64
__global__ __launch_bounds__(256) void gemm1_part(
    const __hip_bfloat16* __restrict__ A, const __hip_bfloat16* __restrict__ B,
    __hip_bfloat16* __restrict__ part)
{
    __shared__ short As[64 * 64];   // 8 KB [64 m][64 k] swizzled
    __shared__ short Bs[64 * 64];   // 8 KB [64 n][64 k] swizzled
    const int K = HIDF, N = HIDF;
    int tid = threadIdx.x;
    int lane = tid & 63;
    int wave = tid >> 6;
    int m0 = blockIdx.y * 64;
    int n0 = blockIdx.x * 64;
    int kbase = blockIdx.z * (K / SPLITK);
    int wr = wave & 1;    // m half (32 rows)
    int wc = wave >> 1;   // n half (32 cols)

    int rf = lane & 15;
    int q = lane >> 4;    // 0..3

    int r0c = tid >> 3,          k0c = (tid & 7) ^ (r0c & 7);
    int r1c = (tid + 256) >> 3,  k1c = (tid & 7) ^ (r1c & 7);
    const char* agp0 = (const char*)A + ((size_t)(m0 + r0c) * K + kbase) * 2 + k0c * 16;
    const char* agp1 = (const char*)A + ((size_t)(m0 + r1c) * K + kbase) * 2 + k1c * 16;
    const char* bgp0 = (const char*)B + ((size_t)(n0 + r0c) * K + kbase) * 2 + k0c * 16;
    const char* bgp1 = (const char*)B + ((size_t)(n0 + r1c) * K + kbase) * 2 + k1c * 16;
    char* alds0 = (char*)As + tid * 16;
    char* alds1 = (char*)As + 4096 + tid * 16;
    char* blds0 = (char*)Bs + tid * 16;
    char* blds1 = (char*)Bs + 4096 + tid * 16;

    floatx4 acc[2][2];
#pragma unroll
    for (int i = 0; i < 2; ++i)
#pragma unroll
        for (int j = 0; j < 2; ++j) acc[i][j] = (floatx4){0.f, 0.f, 0.f, 0.f};

    int rowA0 = wr * 32 + rf;
    int rowB0 = wc * 32 + rf;

    for (int k0 = 0; k0 < K / SPLITK; k0 += G1BK) {
        size_t kb = (size_t)k0 * 2;
        __syncthreads();
        gl_lds16(agp0 + kb, alds0);
        gl_lds16(agp1 + kb, alds1);
        gl_lds16(bgp0 + kb, blds0);
        gl_lds16(bgp1 + kb, blds1);
        __syncthreads();

#pragma unroll
        for (int s = 0; s < 2; ++s) {
            short8 af0, af1, bf0, bf1;
            {
                int row = rowA0;
                af0 = *(const short8*)&As[row * 64 + (((s * 4 + q) ^ (row & 7)) * 8)];
                row = rowA0 + 16;
                af1 = *(const short8*)&As[row * 64 + (((s * 4 + q) ^ (row & 7)) * 8)];
                row = rowB0;
                bf0 = *(const short8*)&Bs[row * 64 + (((s * 4 + q) ^ (row & 7)) * 8)];
                row = rowB0 + 16;
                bf1 = *(const short8*)&Bs[row * 64 + (((s * 4 + q) ^ (row & 7)) * 8)];
            }
            acc[0][0] = __builtin_amdgcn_mfma_f32_16x16x32_bf16(af0, bf0, acc[0][0], 0, 0, 0);
            acc[0][1] = __builtin_amdgcn_mfma_f32_16x16x32_bf16(af0, bf1, acc[0][1], 0, 0, 0);
            acc[1][0] = __builtin_amdgcn_mfma_f32_16x16x32_bf16(af1, bf0, acc[1][0], 0, 0, 0);
            acc[1][1] = __builtin_amdgcn_mfma_f32_16x16x32_bf16(af1, bf1, acc[1][1], 0, 0, 0);
        }
    }

    __hip_bfloat16* pk = part + (size_t)blockIdx.z * BATCH * HIDF;
    int col = lane & 15;
    int rq = (lane >> 4) * 4;
#pragma unroll
    for (int i = 0; i < 2; ++i) {
#pragma unroll
        for (int j = 0; j < 2; ++j) {
            int n = n0 + wc * 32 + j * 16 + col;
#pragma unroll
            for (int r = 0; r < 4; ++r) {
                int m = m0 + wr * 32 + i * 16 + rq + r;
                pk[(size_t)m * N + n] = __float2bfloat16(acc[i][j][r]);
            }
        }
    }
}

// ---------------------------------------------------------------------------
// act_grad_gemm2: per 64b x 64n tile:
//  Phase A: pre1 = part0+part1+bias; h1 (bf16) -> LDS;
//           grad1e = sech^2(pre1) * sum_k E1[n,k]*g0e[b,(n&~31)+k]  -> global
//  Phase B: out2p[ntile][b][d] = h1_tile(64b x 64k) @ wn2b[d, n0:n0+64]^T
// grid (32 ntiles, 16 btiles), 256 threads. h1 never touches global.
// ---------------------------------------------------------------------------
__global__ __launch_bounds__(256) void act_grad_gemm2(
    const __hip_bfloat16* __restrict__ part, const float* __restrict__ bias,
    const float* __restrict__ e1, const float* __restrict__ g0e,
    const __hip_bfloat16* __restrict__ wn2b,
    float* __restrict__ grad1e, float* __restrict__ out2p)
{
    __shared__ char smem[17408 + 8704 + 8192];
    float* g0s = (float*)smem;                          // 64 x 68 floats
    short* h1s = (short*)(smem + 17408);                // 64 x 68 shorts (pad)
    short* Bs2 = (short*)(smem + 17408 + 8704);         // 64 x 64 swizzled

    int tid = threadIdx.x;
    int lane = tid & 63;
    int wave = tid >> 6;
    int n0 = blockIdx.x * 64;
    int b0 = blockIdx.y * 64;

    // early async stage of wn2b k-slice [64 d][n0..n0+64] (XOR swizzle)
    {
        int c0c = tid, c1c = tid + 256;
        int r0 = c0c >> 3, k0c = (c0c & 7) ^ (r0 & 7);
        int r1 = c1c >> 3, k1c = (c1c & 7) ^ (r1 & 7);
        gl_lds16((const char*)wn2b + ((size_t)r0 * HIDF + n0) * 2 + k0c * 16,
                 (char*)Bs2 + c0c * 16);
        gl_lds16((const char*)wn2b + ((size_t)r1 * HIDF + n0) * 2 + k1c * 16,
                 (char*)Bs2 + c1c * 16);
    }

    // stage g0e tile [64 b][64 c] (pad 68)
#pragma unroll
    for (int s = tid; s < 1024; s += 256) {
        int row = s >> 4, c4 = s & 15;
        *(float4*)&g0s[row * 68 + c4 * 4] =
            *(const float4*)&g0e[(size_t)(b0 + row) * HIDF + n0 + c4 * 4];
    }

    int g = tid >> 6;        // b-group 0..3
    int nl = tid & 63;       // local n
    int n = n0 + nl;

    // E1 row for this n into registers (32 floats)
    float4 er[8];
    const float4* e1r = (const float4*)(e1 + (size_t)n * 32);
#pragma unroll
    for (int qq = 0; qq < 8; ++qq) er[qq] = e1r[qq];

    float bv = bias[n];
    int kb2 = nl & 32;
    const __hip_bfloat16* p0 = part;
    const __hip_bfloat16* p1 = part + (size_t)BATCH * HIDF;

    __syncthreads();

    // Phase A
#pragma unroll
    for (int t = 0; t < 16; ++t) {
        int bl = g * 16 + t;
        int b = b0 + bl;
        size_t idx = (size_t)b * HIDF + n;
        float pre = __bfloat162float(p0[idx]) + __bfloat162float(p1[idx]) + bv;
        float th, s2;
        tanh_sech2_(pre, th, s2);
        const float* g0row = &g0s[bl * 68 + kb2];
        float dot = 0.f;
#pragma unroll
        for (int qq = 0; qq < 8; ++qq) {
            float4 gv = *(const float4*)&g0row[qq * 4];
            dot = fmaf(gv.x, er[qq].x, dot);
            dot = fmaf(gv.y, er[qq].y, dot);
            dot = fmaf(gv.z, er[qq].z, dot);
            dot = fmaf(gv.w, er[qq].w, dot);
        }
        __hip_bfloat16 thb = __float2bfloat16(th);
        h1s[bl * 68 + nl] = *(const short*)&thb;
        grad1e[idx] = dot * s2;
    }
    __syncthreads();

    // Phase B: 64b x 64d GEMM over K=64 (the nl slice)
    int rf = lane & 15;
    int q = lane >> 4;
    floatx4 acc2[4];
#pragma unroll
    for (int j = 0; j < 4; ++j) acc2[j] = (floatx4){0.f, 0.f, 0.f, 0.f};

#pragma unroll
    for (int s = 0; s < 2; ++s) {
        int rowa = wave * 16 + rf;
        short8 af = *(const short8*)&h1s[rowa * 68 + s * 32 + q * 8];
#pragma unroll
        for (int j = 0; j < 4; ++j) {
            int rowb = j * 16 + rf;
            int cp = (s * 4 + q) ^ (rowb & 7);
            short8 bfv = *(const short8*)&Bs2[rowb * 64 + cp * 8];
            acc2[j] = __builtin_amdgcn_mfma_f32_16x16x32_bf16(af, bfv, acc2[j], 0, 0, 0);
        }
    }

    float* outk = out2p + (size_t)blockIdx.x * BATCH * DIMN;
    int col = lane & 15;
    int rq = (lane >> 4) * 4;
#pragma unroll
    for (int j = 0; j < 4; ++j) {
#pragma unroll
        for (int r = 0; r < 4; ++r) {
            int m = b0 + wave * 16 + rq + r;
            outk[(size_t)m * DIMN + j * 16 + col] = acc2[j][r];
        }
    }
}

// ---------------------------------------------------------------------------
// tail_gemm0: flows f -> f+1 transition fused with next flow's gemm0.
// gF[b,n] = log( sum_k E2[n,k] * grad1e[b, n*32+k] )   (exp-domain dot)
// ---------------------------------------------------------------------------
__global__ __launch_bounds__(256) void tail_gemm0(
    const float* __restrict__ out2p, const float* __restrict__ b2prev,
    const float* __restrict__ e2prev, const float* __restrict__ grad1e,
    const float* __restrict__ x_cur, const float* __restrict__ gate,
    float* __restrict__ x_next, float* __restrict__ ldj, int accum_ldj,
    const float* __restrict__ wn0T, const float* __restrict__ bias0,
    const float* __restrict__ eg0n, __hip_bfloat16* __restrict__ h0,
    float* __restrict__ g0e)
{
    __shared__ float xs[16][DIMN];
    int tid = threadIdx.x;
    int b0 = blockIdx.y * 16;

    {
        int bl = tid >> 4;            // local batch 0..15
        int n4 = (tid & 15) * 4;
        int b = b0 + bl;
        float4 o4 = *(const float4*)&b2prev[n4];
#pragma unroll
        for (int p = 0; p < NT2; ++p) {
            float4 t = *(const float4*)&out2p[(size_t)p * BATCH * DIMN + (size_t)b * DIMN + n4];
            o4.x += t.x; o4.y += t.y; o4.z += t.z; o4.w += t.w;
        }
        float gt = gate[0];
        float sg = 1.f / (1.f + __expf(-gt));
        float4 xc = *(const float4*)&x_cur[(size_t)b * DIMN + n4];
        float4 xo;
        xo.x = sg * o4.x + (1.f - sg) * xc.x;
        xo.y = sg * o4.y + (1.f - sg) * xc.y;
        xo.z = sg * o4.z + (1.f - sg) * xc.z;
        xo.w = sg * o4.w + (1.f - sg) * xc.w;
        xs[bl][63 - n4] = xo.x;
        xs[bl][62 - n4] = xo.y;
        xs[bl][61 - n4] = xo.z;
        xs[bl][60 - n4] = xo.w;

        if (blockIdx.x == 0) {
            float4 rv; rv.x = xo.w; rv.y = xo.z; rv.z = xo.y; rv.w = xo.x;
            *(float4*)&x_next[(size_t)b * DIMN + (60 - n4)] = rv;

            float spgt = softplusf_(gt);
            float cl = 0.f;
#pragma unroll
            for (int q = 0; q < 4; ++q) {
                int n = n4 + q;
                const float4* gr = (const float4*)&grad1e[(size_t)b * HIDF + n * 32];
                const float4* gc = (const float4*)&e2prev[n * 32];
                float s = 0.f;
#pragma unroll
                for (int u = 0; u < 8; ++u) {
                    float4 a = gr[u], c = gc[u];
                    s = fmaf(a.x, c.x, s);
                    s = fmaf(a.y, c.y, s);
                    s = fmaf(a.z, c.z, s);
                    s = fmaf(a.w, c.w, s);
                }
                float gF = __logf(s);
                cl += softplusf_(gF + gt) - spgt;
            }
            cl += __shfl_xor(cl, 1, 64);
            cl += __shfl_xor(cl, 2, 64);
            cl += __shfl_xor(cl, 4, 64);
            cl += __shfl_xor(cl, 8, 64);
            if ((tid & 15) == 0) ldj[b] = accum_ldj ? (ldj[b] + cl) : cl;
        }
    }
    __syncthreads();

    int n = blockIdx.x * 256 + tid;
    gemm0_core(xs, b0, n, wn0T, bias0, eg0n, h0, g0e);
}

// ---------------------------------------------------------------------------
// tail_final (flow 2): out[b] = ldj[b] + sum_n(gF - 0.5*o^2 - 0.5*log(2pi))
// ---------------------------------------------------------------------------
__global__ __launch_bounds__(256) void tail_final(
    const float* __restrict__ out2p, const float* __restrict__ b2,
    const float* __restrict__ e2, const float* __restrict__ grad1e,
    const float* __restrict__ ldj, float* __restrict__ out)
{
    int tid = threadIdx.x;
    int b = blockIdx.x * 4 + (tid >> 6);
    int n = tid & 63;

    float o = b2[n];
#pragma unroll
    for (int p = 0; p < NT2; ++p)
        o += out2p[(size_t)p * BATCH * DIMN + (size_t)b * DIMN + n];

    const float4* gr = (const float4*)(grad1e + (size_t)b * HIDF + n * 32);
    const float4* gc = (const float4*)(e2 + n * 32);
    float s = 0.f;
#pragma unroll
    for (int q = 0; q < 8; ++q) {
        float4 a = gr[q], c = gc[q];
        s = fmaf(a.x, c.x, s);
        s = fmaf(a.y, c.y, s);
        s = fmaf(a.z, c.z, s);
        s = fmaf(a.w, c.w, s);
    }
    float gF = __logf(fmaxf(s, 1e-45f));

    float contrib = gF - 0.5f * o * o - 0.91893853320467274f; // -0.5*log(2pi)
    for (int off = 32; off > 0; off >>= 1) contrib += __shfl_xor(contrib, off, 64);
    if (n == 0) out[b] = ldj[b] + contrib;
}

// ---------------------------------------------------------------------------
extern "C" void kernel_launch(void* const* d_in, const int* in_sizes, int n_in,
                              void* d_out, int out_size, void* d_ws, size_t ws_size,
                              hipStream_t stream)
{
    (void)in_sizes; (void)n_in; (void)out_size; (void)ws_size;

    const float* x = (const float*)d_in[0];
    const float* gates[2] = { (const float*)d_in[28], (const float*)d_in[29] };

    char* ws = (char*)d_ws;
    size_t ofs = 0;
    auto alloc = [&](size_t bytes) { char* p = ws + ofs; ofs += (bytes + 255) & ~(size_t)255; return p; };

    __hip_bfloat16* wn1_all  = (__hip_bfloat16*)alloc((size_t)3 * HIDF * HIDF * 2);  // 24 MB
    __hip_bfloat16* wn2b_all = (__hip_bfloat16*)alloc((size_t)3 * DIMN * HIDF * 2);
    float* wn0T_all = (float*)alloc((size_t)3 * DIMN * HIDF * 4);
    float* eg0_all  = (float*)alloc((size_t)3 * HIDF * 4);
    float* e1_all   = (float*)alloc((size_t)3 * HIDF * 32 * 4);
    float* e2_all   = (float*)alloc((size_t)3 * DIMN * 32 * 4);
    __hip_bfloat16* h0   = (__hip_bfloat16*)alloc((size_t)BATCH * HIDF * 2);
    __hip_bfloat16* part = (__hip_bfloat16*)alloc((size_t)SPLITK * BATCH * HIDF * 2); // 8 MB
    float* g0e    = (float*)alloc((size_t)BATCH * HIDF * 4);
    float* grad1e = (float*)alloc((size_t)BATCH * HIDF * 4);
    float* out2p  = (float*)alloc((size_t)NT2 * BATCH * DIMN * 4);                    // 8 MB
    float* x1     = (float*)alloc((size_t)BATCH * DIMN * 4);
    float* x2     = (float*)alloc((size_t)BATCH * DIMN * 4);
    float* ldj    = (float*)alloc(BATCH * 4);
    float* outp   = (float*)d_out;

    auto W = [&](int f, int i) { return (const float*)d_in[1 + f * 9 + i]; };

    PrepIn p0 = { W(0,0), W(0,1), W(0,3), W(0,4), W(0,6), W(0,7) };
    PrepIn p1 = { W(1,0), W(1,1), W(1,3), W(1,4), W(1,6), W(1,7) };
    PrepIn p2 = { W(2,0), W(2,1), W(2,3), W(2,4), W(2,6), W(2,7) };

    prep_mega<<<dim3(3 * 4160), dim3(64), 0, stream>>>(
        p0, p1, p2, wn0T_all, eg0_all, wn1_all, e1_all, wn2b_all, e2_all);

    gemm0_act<<<dim3(8, BATCH / 16), dim3(256), 0, stream>>>(
        x, wn0T_all, W(0,2), eg0_all, h0, g0e);

    const float* xcur = x;
    float* xnexts[2] = { x1, x2 };

    for (int f = 0; f < 3; ++f) {
        size_t fo1 = (size_t)f * HIDF * HIDF;
        size_t fo2 = (size_t)f * DIMN * HIDF;

        gemm1_part<<<dim3(HIDF / 64, BATCH / 64, SPLITK), dim3(256), 0, stream>>>(
            h0, wn1_all + fo1, part);

        act_grad_gemm2<<<dim3(HIDF / 64, BATCH / 64), dim3(256), 0, stream>>>(
            part, W(f,5), e1_all + (size_t)f * HIDF * 32, g0e,
            wn2b_all + fo2, grad1e, out2p);

        if (f < 2) {
            tail_gemm0<<<dim3(8, BATCH / 16), dim3(256), 0, stream>>>(
                out2p, W(f,8), e2_all + (size_t)f * DIMN * 32, grad1e,
                xcur, gates[f], xnexts[f], ldj, f,
                wn0T_all + (size_t)(f + 1) * DIMN * HIDF, W(f + 1, 2),
                eg0_all + (size_t)(f + 1) * HIDF, h0, g0e);
            xcur = xnexts[f];
        } else {
            tail_final<<<dim3(BATCH / 4), dim3(256), 0, stream>>>(
                out2p, W(2,8), e2_all + (size_t)2 * DIMN * 32, grad1e, ldj, outp);
        }
    }
}

// Round 15
// 295.103 us; speedup vs baseline: 1.2886x; 1.0977x over previous
//
#include <hip/hip_runtime.h>
#include <hip/hip_bf16.h>
#include <math.h>

// ---------------------------------------------------------------------------
// BNAF flow (DIM=64, HID=32, B=1024).  R15: tail_gemm0 split into tail_trans
// (single-pass out2p reduction + gate + reversal + ldj) and plain gemm0_act,
// removing the 8x-replicated 38MB partial fetch. 13 dispatches.
// ---------------------------------------------------------------------------

#define DIMN 64
#define BATCH 1024
#define HIDF 2048   // DIM*HID
#define SPLITK 2
#define NT2 32      // out2 partial count (= HIDF/64 n-tiles)

typedef __attribute__((ext_vector_type(8))) short short8;
typedef __attribute__((ext_vector_type(4))) float floatx4;

__device__ __forceinline__ float softplusf_(float t) {
    return fmaxf(t, 0.f) + log1pf(__expf(-fabsf(t)));
}

__device__ __forceinline__ void gl_lds16(const void* g, void* l) {
    __builtin_amdgcn_global_load_lds(
        (const __attribute__((address_space(1))) unsigned int*)g,
        (__attribute__((address_space(3))) unsigned int*)l, 16, 0, 0);
}

// tanh + sech^2 from ONE exp:  t = e^{-2|p|}; tanh = sign(p)(1-t)/(1+t);
// sech^2 = 4t/(1+t)^2.
__device__ __forceinline__ void tanh_sech2_(float p, float& th, float& s2) {
    float t = __expf(-2.f * fabsf(p));
    float opt = 1.f + t;
    float inv = 1.f / opt;
    th = copysignf((1.f - t) * inv, p);
    s2 = 4.f * t * inv * inv;
}

// ---------------------------------------------------------------------------
// prep row worker: one wave per output row r of W (out_f x INF).
//  wn = exp(dw)*w/sqrt(wsn); eg[r*ib+k] = exp(dw + W[r][c0+k] - 0.5 log wsn)
// ---------------------------------------------------------------------------
template<int INF>
__device__ __forceinline__ void prep_row(
    const float* __restrict__ W, const float* __restrict__ dw,
    void* __restrict__ wn_out, float* __restrict__ eg,
    int r, int lane, int out_f, int ob, int ib, int transpose, int bf16out)
{
    constexpr int NI = INF / 64;
    int d = r / ob;
    int c0 = d * ib;
    int c1 = c0 + ib;
    const float* Wr = W + (size_t)r * INF;

    float vv[NI];
    float ss = 0.f;
#pragma unroll
    for (int i = 0; i < NI; ++i) {
        int c = lane + i * 64;
        float wraw = Wr[c];
        float wv = (c < c0) ? wraw : ((c < c1) ? __expf(wraw) : 0.f);
        vv[i] = wv;
        ss += wv * wv;
    }
    for (int off = 32; off > 0; off >>= 1) ss += __shfl_xor(ss, off, 64);

    float dwr = dw[r];
    float scale = __expf(dwr) / sqrtf(ss);
    float logt = dwr - 0.5f * __logf(ss);

#pragma unroll
    for (int i = 0; i < NI; ++i) {
        int c = lane + i * 64;
        float val = scale * vv[i];
        if (bf16out) {
            ((__hip_bfloat16*)wn_out)[(size_t)r * INF + c] = __float2bfloat16(val);
        } else if (transpose) {
            ((float*)wn_out)[(size_t)c * out_f + r] = val;
        } else {
            ((float*)wn_out)[(size_t)r * INF + c] = val;
        }
    }
    if (lane < ib) eg[(size_t)r * ib + lane] = __expf(logt + Wr[c0 + lane]);
}

struct PrepIn { const float *W0, *dw0, *W1, *dw1, *W2, *dw2; };

// all three flows' preps in ONE launch: grid 3 * (2048+2048+64) = 12480
__global__ __launch_bounds__(64) void prep_mega(
    PrepIn p0, PrepIn p1, PrepIn p2,
    float* __restrict__ wn0T_all, float* __restrict__ eg0_all,
    __hip_bfloat16* __restrict__ wn1_all, float* __restrict__ e1_all,
    __hip_bfloat16* __restrict__ wn2b_all, float* __restrict__ e2_all)
{
    int blk = blockIdx.x;
    int lane = threadIdx.x;
    int f = blk / 4160;
    int rem = blk - f * 4160;
    PrepIn P = (f == 0) ? p0 : ((f == 1) ? p1 : p2);

    float* wn0T = wn0T_all + (size_t)f * DIMN * HIDF;
    float* eg0  = eg0_all  + (size_t)f * HIDF;
    __hip_bfloat16* wn1 = wn1_all + (size_t)f * HIDF * HIDF;
    float* e1   = e1_all   + (size_t)f * HIDF * 32;
    __hip_bfloat16* wn2b = wn2b_all + (size_t)f * DIMN * HIDF;
    float* e2   = e2_all   + (size_t)f * DIMN * 32;

    if (rem < HIDF) {
        prep_row<DIMN>(P.W0, P.dw0, wn0T, eg0, rem, lane, HIDF, 32, 1, 1, 0);
    } else if (rem < 2 * HIDF) {
        prep_row<HIDF>(P.W1, P.dw1, wn1, e1, rem - HIDF, lane, HIDF, 32, 32, 0, 1);
    } else {
        prep_row<HIDF>(P.W2, P.dw2, wn2b, e2, rem - 2 * HIDF, lane, DIMN, 1, 32, 0, 1);
    }
}

// ---------------------------------------------------------------------------
// gemm0_act: pre0 = x @ wn0T + b0 ; h0 = tanh(pre0) bf16;
// g0e[b,n] = eg0[n] * sech^2(pre0). grid (8, 64), 256 threads.
// ---------------------------------------------------------------------------
__global__ __launch_bounds__(256) void gemm0_act(
    const float* __restrict__ xin, const float* __restrict__ wn0T,
    const float* __restrict__ bias, const float* __restrict__ eg0,
    __hip_bfloat16* __restrict__ h0, float* __restrict__ g0e)
{
    __shared__ float xs[16][DIMN];
    int b0 = blockIdx.y * 16;
    {
        const float4* src = (const float4*)(xin + (size_t)b0 * DIMN);
        ((float4*)xs)[threadIdx.x] = src[threadIdx.x];
    }
    __syncthreads();
    int n = blockIdx.x * 256 + threadIdx.x;

    float acc[16];
#pragma unroll
    for (int j = 0; j < 16; ++j) acc[j] = 0.f;

#pragma unroll 4
    for (int c4 = 0; c4 < 16; ++c4) {
        int c = c4 * 4;
        float w0 = wn0T[(size_t)(c + 0) * HIDF + n];
        float w1 = wn0T[(size_t)(c + 1) * HIDF + n];
        float w2 = wn0T[(size_t)(c + 2) * HIDF + n];
        float w3 = wn0T[(size_t)(c + 3) * HIDF + n];
#pragma unroll
        for (int j = 0; j < 16; ++j) {
            float4 x4 = *(const float4*)&xs[j][c];
            acc[j] = fmaf(x4.x, w0, acc[j]);
            acc[j] = fmaf(x4.y, w1, acc[j]);
            acc[j] = fmaf(x4.z, w2, acc[j]);
            acc[j] = fmaf(x4.w, w3, acc[j]);
        }
    }
    float bv = bias[n], egv = eg0[n];
#pragma unroll
    for (int j = 0; j < 16; ++j) {
        float p = acc[j] + bv;
        float th, s2;
        tanh_sech2_(p, th, s2);
        size_t idx = (size_t)(b0 + j) * HIDF + n;
        h0[idx] = __float2bfloat16(th);
        g0e[idx] = egv * s2;
    }
}

// ---------------------------------------------------------------------------
// gemm1_part: partial[kc][m][n] = sum_{k in chunk kc} h0[m,k]*wn1[n,k] (bf16)
// 64x64 tile, BK=64, XOR chunk swizzle kc^(row&7), flat scalar staging
// pointers (VGPR-lean), trivial epilogue. grid (32, 16, 2) = 1024 blocks.
// ---------------------------------------------------------------------------
#define G1BK 64
__global__ __launch_bounds__(256) void gemm1_part(
    const __hip_bfloat16* __restrict__ A, const __hip_bfloat16* __restrict__ B,
    __hip_bfloat16* __restrict__ part)
{
    __shared__ short As[64 * 64];   // 8 KB [64 m][64 k] swizzled
    __shared__ short Bs[64 * 64];   // 8 KB [64 n][64 k] swizzled
    const int K = HIDF, N = HIDF;
    int tid = threadIdx.x;
    int lane = tid & 63;
    int wave = tid >> 6;
    int m0 = blockIdx.y * 64;
    int n0 = blockIdx.x * 64;
    int kbase = blockIdx.z * (K / SPLITK);
    int wr = wave & 1;    // m half (32 rows)
    int wc = wave >> 1;   // n half (32 cols)

    int rf = lane & 15;
    int q = lane >> 4;    // 0..3

    int r0c = tid >> 3,          k0c = (tid & 7) ^ (r0c & 7);
    int r1c = (tid + 256) >> 3,  k1c = (tid & 7) ^ (r1c & 7);
    const char* agp0 = (const char*)A + ((size_t)(m0 + r0c) * K + kbase) * 2 + k0c * 16;
    const char* agp1 = (const char*)A + ((size_t)(m0 + r1c) * K + kbase) * 2 + k1c * 16;
    const char* bgp0 = (const char*)B + ((size_t)(n0 + r0c) * K + kbase) * 2 + k0c * 16;
    const char* bgp1 = (const char*)B + ((size_t)(n0 + r1c) * K + kbase) * 2 + k1c * 16;
    char* alds0 = (char*)As + tid * 16;
    char* alds1 = (char*)As + 4096 + tid * 16;
    char* blds0 = (char*)Bs + tid * 16;
    char* blds1 = (char*)Bs + 4096 + tid * 16;

    floatx4 acc[2][2];
#pragma unroll
    for (int i = 0; i < 2; ++i)
#pragma unroll
        for (int j = 0; j < 2; ++j) acc[i][j] = (floatx4){0.f, 0.f, 0.f, 0.f};

    int rowA0 = wr * 32 + rf;
    int rowB0 = wc * 32 + rf;

    for (int k0 = 0; k0 < K / SPLITK; k0 += G1BK) {
        size_t kb = (size_t)k0 * 2;
        __syncthreads();
        gl_lds16(agp0 + kb, alds0);
        gl_lds16(agp1 + kb, alds1);
        gl_lds16(bgp0 + kb, blds0);
        gl_lds16(bgp1 + kb, blds1);
        __syncthreads();

#pragma unroll
        for (int s = 0; s < 2; ++s) {
            short8 af0, af1, bf0, bf1;
            {
                int row = rowA0;
                af0 = *(const short8*)&As[row * 64 + (((s * 4 + q) ^ (row & 7)) * 8)];
                row = rowA0 + 16;
                af1 = *(const short8*)&As[row * 64 + (((s * 4 + q) ^ (row & 7)) * 8)];
                row = rowB0;
                bf0 = *(const short8*)&Bs[row * 64 + (((s * 4 + q) ^ (row & 7)) * 8)];
                row = rowB0 + 16;
                bf1 = *(const short8*)&Bs[row * 64 + (((s * 4 + q) ^ (row & 7)) * 8)];
            }
            acc[0][0] = __builtin_amdgcn_mfma_f32_16x16x32_bf16(af0, bf0, acc[0][0], 0, 0, 0);
            acc[0][1] = __builtin_amdgcn_mfma_f32_16x16x32_bf16(af0, bf1, acc[0][1], 0, 0, 0);
            acc[1][0] = __builtin_amdgcn_mfma_f32_16x16x32_bf16(af1, bf0, acc[1][0], 0, 0, 0);
            acc[1][1] = __builtin_amdgcn_mfma_f32_16x16x32_bf16(af1, bf1, acc[1][1], 0, 0, 0);
        }
    }

    __hip_bfloat16* pk = part + (size_t)blockIdx.z * BATCH * HIDF;
    int col = lane & 15;
    int rq = (lane >> 4) * 4;
#pragma unroll
    for (int i = 0; i < 2; ++i) {
#pragma unroll
        for (int j = 0; j < 2; ++j) {
            int n = n0 + wc * 32 + j * 16 + col;
#pragma unroll
            for (int r = 0; r < 4; ++r) {
                int m = m0 + wr * 32 + i * 16 + rq + r;
                pk[(size_t)m * N + n] = __float2bfloat16(acc[i][j][r]);
            }
        }
    }
}

// ---------------------------------------------------------------------------
// act_grad_gemm2: per 64b x 64n tile:
//  Phase A: pre1 = part0+part1+bias; h1 (bf16) -> LDS;
//           grad1e = sech^2(pre1) * sum_k E1[n,k]*g0e[b,(n&~31)+k]  -> global
//  Phase B: out2p[ntile][b][d] = h1_tile(64b x 64k) @ wn2b[d, n0:n0+64]^T
// grid (32 ntiles, 16 btiles), 256 threads. h1 never touches global.
// ---------------------------------------------------------------------------
__global__ __launch_bounds__(256) void act_grad_gemm2(
    const __hip_bfloat16* __restrict__ part, const float* __restrict__ bias,
    const float* __restrict__ e1, const float* __restrict__ g0e,
    const __hip_bfloat16* __restrict__ wn2b,
    float* __restrict__ grad1e, float* __restrict__ out2p)
{
    __shared__ char smem[17408 + 8704 + 8192];
    float* g0s = (float*)smem;                          // 64 x 68 floats
    short* h1s = (short*)(smem + 17408);                // 64 x 68 shorts (pad)
    short* Bs2 = (short*)(smem + 17408 + 8704);         // 64 x 64 swizzled

    int tid = threadIdx.x;
    int lane = tid & 63;
    int wave = tid >> 6;
    int n0 = blockIdx.x * 64;
    int b0 = blockIdx.y * 64;

    // early async stage of wn2b k-slice [64 d][n0..n0+64] (XOR swizzle)
    {
        int c0c = tid, c1c = tid + 256;
        int r0 = c0c >> 3, k0c = (c0c & 7) ^ (r0 & 7);
        int r1 = c1c >> 3, k1c = (c1c & 7) ^ (r1 & 7);
        gl_lds16((const char*)wn2b + ((size_t)r0 * HIDF + n0) * 2 + k0c * 16,
                 (char*)Bs2 + c0c * 16);
        gl_lds16((const char*)wn2b + ((size_t)r1 * HIDF + n0) * 2 + k1c * 16,
                 (char*)Bs2 + c1c * 16);
    }

    // stage g0e tile [64 b][64 c] (pad 68)
#pragma unroll
    for (int s = tid; s < 1024; s += 256) {
        int row = s >> 4, c4 = s & 15;
        *(float4*)&g0s[row * 68 + c4 * 4] =
            *(const float4*)&g0e[(size_t)(b0 + row) * HIDF + n0 + c4 * 4];
    }

    int g = tid >> 6;        // b-group 0..3
    int nl = tid & 63;       // local n
    int n = n0 + nl;

    // E1 row for this n into registers (32 floats)
    float4 er[8];
    const float4* e1r = (const float4*)(e1 + (size_t)n * 32);
#pragma unroll
    for (int qq = 0; qq < 8; ++qq) er[qq] = e1r[qq];

    float bv = bias[n];
    int kb2 = nl & 32;
    const __hip_bfloat16* p0 = part;
    const __hip_bfloat16* p1 = part + (size_t)BATCH * HIDF;

    __syncthreads();

    // Phase A
#pragma unroll
    for (int t = 0; t < 16; ++t) {
        int bl = g * 16 + t;
        int b = b0 + bl;
        size_t idx = (size_t)b * HIDF + n;
        float pre = __bfloat162float(p0[idx]) + __bfloat162float(p1[idx]) + bv;
        float th, s2;
        tanh_sech2_(pre, th, s2);
        const float* g0row = &g0s[bl * 68 + kb2];
        float dot = 0.f;
#pragma unroll
        for (int qq = 0; qq < 8; ++qq) {
            float4 gv = *(const float4*)&g0row[qq * 4];
            dot = fmaf(gv.x, er[qq].x, dot);
            dot = fmaf(gv.y, er[qq].y, dot);
            dot = fmaf(gv.z, er[qq].z, dot);
            dot = fmaf(gv.w, er[qq].w, dot);
        }
        __hip_bfloat16 thb = __float2bfloat16(th);
        h1s[bl * 68 + nl] = *(const short*)&thb;
        grad1e[idx] = dot * s2;
    }
    __syncthreads();

    // Phase B: 64b x 64d GEMM over K=64 (the nl slice)
    int rf = lane & 15;
    int q = lane >> 4;
    floatx4 acc2[4];
#pragma unroll
    for (int j = 0; j < 4; ++j) acc2[j] = (floatx4){0.f, 0.f, 0.f, 0.f};

#pragma unroll
    for (int s = 0; s < 2; ++s) {
        int rowa = wave * 16 + rf;
        short8 af = *(const short8*)&h1s[rowa * 68 + s * 32 + q * 8];
#pragma unroll
        for (int j = 0; j < 4; ++j) {
            int rowb = j * 16 + rf;
            int cp = (s * 4 + q) ^ (rowb & 7);
            short8 bfv = *(const short8*)&Bs2[rowb * 64 + cp * 8];
            acc2[j] = __builtin_amdgcn_mfma_f32_16x16x32_bf16(af, bfv, acc2[j], 0, 0, 0);
        }
    }

    float* outk = out2p + (size_t)blockIdx.x * BATCH * DIMN;
    int col = lane & 15;
    int rq = (lane >> 4) * 4;
#pragma unroll
    for (int j = 0; j < 4; ++j) {
#pragma unroll
        for (int r = 0; r < 4; ++r) {
            int m = b0 + wave * 16 + rq + r;
            outk[(size_t)m * DIMN + j * 16 + col] = acc2[j][r];
        }
    }
}

// ---------------------------------------------------------------------------
// tail_trans: one wave per batch row. Single-pass partial reduction:
//  o = b2 + sum_p out2p[p][b][n]; xo = gate-mix; x_next[b][63-n] = xo;
//  gF = log(sum_k E2[n,k]*grad1e[b,n*32+k]); ldj write/accum.
// grid 256 (4 b per block), 256 threads.
// ---------------------------------------------------------------------------
__global__ __launch_bounds__(256) void tail_trans(
    const float* __restrict__ out2p, const float* __restrict__ b2,
    const float* __restrict__ e2, const float* __restrict__ grad1e,
    const float* __restrict__ x_cur, const float* __restrict__ gate,
    float* __restrict__ x_next, float* __restrict__ ldj, int accum_ldj)
{
    int tid = threadIdx.x;
    int b = blockIdx.x * 4 + (tid >> 6);
    int n = tid & 63;

    float o = b2[n];
#pragma unroll
    for (int p = 0; p < NT2; ++p)
        o += out2p[(size_t)p * BATCH * DIMN + (size_t)b * DIMN + n];

    float gt = gate[0];
    float sg = 1.f / (1.f + __expf(-gt));
    float xo = sg * o + (1.f - sg) * x_cur[(size_t)b * DIMN + n];
    x_next[(size_t)b * DIMN + (63 - n)] = xo;

    const float4* gr = (const float4*)(grad1e + (size_t)b * HIDF + n * 32);
    const float4* gc = (const float4*)(e2 + n * 32);
    float s = 0.f;
#pragma unroll
    for (int q = 0; q < 8; ++q) {
        float4 a = gr[q], c = gc[q];
        s = fmaf(a.x, c.x, s);
        s = fmaf(a.y, c.y, s);
        s = fmaf(a.z, c.z, s);
        s = fmaf(a.w, c.w, s);
    }
    float gF = __logf(fmaxf(s, 1e-45f));
    float contrib = softplusf_(gF + gt) - softplusf_(gt);
    for (int off = 32; off > 0; off >>= 1) contrib += __shfl_xor(contrib, off, 64);
    if (n == 0) ldj[b] = accum_ldj ? (ldj[b] + contrib) : contrib;
}

// ---------------------------------------------------------------------------
// tail_final (flow 2): out[b] = ldj[b] + sum_n(gF - 0.5*o^2 - 0.5*log(2pi))
// ---------------------------------------------------------------------------
__global__ __launch_bounds__(256) void tail_final(
    const float* __restrict__ out2p, const float* __restrict__ b2,
    const float* __restrict__ e2, const float* __restrict__ grad1e,
    const float* __restrict__ ldj, float* __restrict__ out)
{
    int tid = threadIdx.x;
    int b = blockIdx.x * 4 + (tid >> 6);
    int n = tid & 63;

    float o = b2[n];
#pragma unroll
    for (int p = 0; p < NT2; ++p)
        o += out2p[(size_t)p * BATCH * DIMN + (size_t)b * DIMN + n];

    const float4* gr = (const float4*)(grad1e + (size_t)b * HIDF + n * 32);
    const float4* gc = (const float4*)(e2 + n * 32);
    float s = 0.f;
#pragma unroll
    for (int q = 0; q < 8; ++q) {
        float4 a = gr[q], c = gc[q];
        s = fmaf(a.x, c.x, s);
        s = fmaf(a.y, c.y, s);
        s = fmaf(a.z, c.z, s);
        s = fmaf(a.w, c.w, s);
    }
    float gF = __logf(fmaxf(s, 1e-45f));

    float contrib = gF - 0.5f * o * o - 0.91893853320467274f; // -0.5*log(2pi)
    for (int off = 32; off > 0; off >>= 1) contrib += __shfl_xor(contrib, off, 64);
    if (n == 0) out[b] = ldj[b] + contrib;
}

// ---------------------------------------------------------------------------
extern "C" void kernel_launch(void* const* d_in, const int* in_sizes, int n_in,
                              void* d_out, int out_size, void* d_ws, size_t ws_size,
                              hipStream_t stream)
{
    (void)in_sizes; (void)n_in; (void)out_size; (void)ws_size;

    const float* x = (const float*)d_in[0];
    const float* gates[2] = { (const float*)d_in[28], (const float*)d_in[29] };

    char* ws = (char*)d_ws;
    size_t ofs = 0;
    auto alloc = [&](size_t bytes) { char* p = ws + ofs; ofs += (bytes + 255) & ~(size_t)255; return p; };

    __hip_bfloat16* wn1_all  = (__hip_bfloat16*)alloc((size_t)3 * HIDF * HIDF * 2);  // 24 MB
    __hip_bfloat16* wn2b_all = (__hip_bfloat16*)alloc((size_t)3 * DIMN * HIDF * 2);
    float* wn0T_all = (float*)alloc((size_t)3 * DIMN * HIDF * 4);
    float* eg0_all  = (float*)alloc((size_t)3 * HIDF * 4);
    float* e1_all   = (float*)alloc((size_t)3 * HIDF * 32 * 4);
    float* e2_all   = (float*)alloc((size_t)3 * DIMN * 32 * 4);
    __hip_bfloat16* h0   = (__hip_bfloat16*)alloc((size_t)BATCH * HIDF * 2);
    __hip_bfloat16* part = (__hip_bfloat16*)alloc((size_t)SPLITK * BATCH * HIDF * 2); // 8 MB
    float* g0e    = (float*)alloc((size_t)BATCH * HIDF * 4);
    float* grad1e = (float*)alloc((size_t)BATCH * HIDF * 4);
    float* out2p  = (float*)alloc((size_t)NT2 * BATCH * DIMN * 4);                    // 8 MB
    float* x1     = (float*)alloc((size_t)BATCH * DIMN * 4);
    float* x2     = (float*)alloc((size_t)BATCH * DIMN * 4);
    float* ldj    = (float*)alloc(BATCH * 4);
    float* outp   = (float*)d_out;

    auto W = [&](int f, int i) { return (const float*)d_in[1 + f * 9 + i]; };

    PrepIn p0 = { W(0,0), W(0,1), W(0,3), W(0,4), W(0,6), W(0,7) };
    PrepIn p1 = { W(1,0), W(1,1), W(1,3), W(1,4), W(1,6), W(1,7) };
    PrepIn p2 = { W(2,0), W(2,1), W(2,3), W(2,4), W(2,6), W(2,7) };

    prep_mega<<<dim3(3 * 4160), dim3(64), 0, stream>>>(
        p0, p1, p2, wn0T_all, eg0_all, wn1_all, e1_all, wn2b_all, e2_all);

    gemm0_act<<<dim3(8, BATCH / 16), dim3(256), 0, stream>>>(
        x, wn0T_all, W(0,2), eg0_all, h0, g0e);

    const float* xcur = x;
    float* xnexts[2] = { x1, x2 };

    for (int f = 0; f < 3; ++f) {
        size_t fo1 = (size_t)f * HIDF * HIDF;
        size_t fo2 = (size_t)f * DIMN * HIDF;

        gemm1_part<<<dim3(HIDF / 64, BATCH / 64, SPLITK), dim3(256), 0, stream>>>(
            h0, wn1_all + fo1, part);

        act_grad_gemm2<<<dim3(HIDF / 64, BATCH / 64), dim3(256), 0, stream>>>(
            part, W(f,5), e1_all + (size_t)f * HIDF * 32, g0e,
            wn2b_all + fo2, grad1e, out2p);

        if (f < 2) {
            tail_trans<<<dim3(BATCH / 4), dim3(256), 0, stream>>>(
                out2p, W(f,8), e2_all + (size_t)f * DIMN * 32, grad1e,
                xcur, gates[f], xnexts[f], ldj, f);

            gemm0_act<<<dim3(8, BATCH / 16), dim3(256), 0, stream>>>(
                xnexts[f], wn0T_all + (size_t)(f + 1) * DIMN * HIDF, W(f + 1, 2),
                eg0_all + (size_t)(f + 1) * HIDF, h0, g0e);

            xcur = xnexts[f];
        } else {
            tail_final<<<dim3(BATCH / 4), dim3(256), 0, stream>>>(
                out2p, W(2,8), e2_all + (size_t)2 * DIMN * 32, grad1e, ldj, outp);
        }
    }
}